// Round 1
// baseline (417.232 us; speedup 1.0000x reference)
//
#include <hip/hip_runtime.h>

// ---------------------------------------------------------------------------
// GAT encoder: x --GATConv(2 heads,128)--> ELU --> {GATConv mu, GATConv ls}
// N=50000, E=800000 (+self loops). fp32 in/out. Edges int32 w/ int64 detect.
// Round 8:
//  * k_agg split by column-half with XCD-group affinity (blockIdx%8 -> XCD
//    round-robin): half 0 (cols 0-127) on XCDs 0-3, half 1 on XCDs 4-7.
//    Each 256B half-row is then fetched by ~4 XCDs instead of ~7 fetching
//    512B rows -> predicted FETCH 210MB -> ~110MB per dispatch.
//    Lanes own 2 channels (4B gather loads); edge weights recomputed per
//    half (as[] is L2-resident, VALU had 56% headroom).
//  * MFMA GEMM stages Wt chunks in LDS (20KB, pad-40 rows); alphas fused
//    into GEMM epilogue from fp32 accs (round 7).
// ---------------------------------------------------------------------------

typedef unsigned short u16;
typedef unsigned int u32;
typedef _Float16 f16;
typedef f16 f16x8 __attribute__((ext_vector_type(8)));
typedef float f32x4v __attribute__((ext_vector_type(4)));

__device__ __forceinline__ u16 f2h(float f) {
    union { f16 h; u16 u; } t;
    t.h = (f16)f;
    return t.u;
}
__device__ __forceinline__ float2 loadh2(const u16* __restrict__ p, size_t i) {
    union { u32 u; f16 h[2]; } t;
    t.u = *(const u32*)(p + i);
    return make_float2((float)t.h[0], (float)t.h[1]);
}
__device__ __forceinline__ void store2h(u16* __restrict__ p, size_t i, float a,
                                        float b) {
    union { u32 u; f16 h[2]; } t;
    t.h[0] = (f16)a;
    t.h[1] = (f16)b;
    *(u32*)(p + i) = t.u;
}
__device__ __forceinline__ void store4(float* __restrict__ p, size_t i, float4 v) {
    *(float4*)(p + i) = v;
}
__device__ __forceinline__ void store4(u16* __restrict__ p, size_t i, float4 v) {
    union { uint2 u; f16 h[4]; } t;
    t.h[0] = (f16)v.x; t.h[1] = (f16)v.y; t.h[2] = (f16)v.z; t.h[3] = (f16)v.w;
    *(uint2*)(p + i) = t.u;
}

// ---------------- edge dtype detect + normalize (+degree count) --------------
__global__ __launch_bounds__(256) void k_detect(const u32* __restrict__ ebuf,
                                                int* __restrict__ flag) {
    __shared__ int nz;
    if (threadIdx.x == 0) nz = 0;
    __syncthreads();
    if (ebuf[2 * threadIdx.x + 1] != 0u) atomicAdd(&nz, 1);
    __syncthreads();
    if (threadIdx.x == 0) *flag = (nz == 0) ? 1 : 0;
}

__global__ __launch_bounds__(256) void k_extract(const u32* __restrict__ ebuf, int E,
                                                 const int* __restrict__ flag,
                                                 int* __restrict__ se,
                                                 int* __restrict__ de,
                                                 int* __restrict__ deg) {
    int e = blockIdx.x * 256 + threadIdx.x;
    if (e >= E) return;
    int s, d;
    if (*flag) {  // int64 layout
        s = (int)ebuf[2 * (size_t)e];
        d = (int)ebuf[2 * ((size_t)E + (size_t)e)];
    } else {  // int32 layout
        s = (int)ebuf[e];
        d = (int)ebuf[(size_t)E + (size_t)e];
    }
    se[e] = s;
    de[e] = d;
    atomicAdd(&deg[d], 1);
}

// ---------------- CSR build ----------------
__global__ __launch_bounds__(256) void k_scan_a(const int* __restrict__ deg, int n,
                                                int* __restrict__ bsum) {
    __shared__ int s[256];
    int i = blockIdx.x * 256 + threadIdx.x;
    s[threadIdx.x] = (i < n) ? deg[i] : 0;
    __syncthreads();
    for (int st = 128; st > 0; st >>= 1) {
        if (threadIdx.x < st) s[threadIdx.x] += s[threadIdx.x + st];
        __syncthreads();
    }
    if (threadIdx.x == 0) bsum[blockIdx.x] = s[0];
}

__global__ __launch_bounds__(256) void k_scan_b(int* __restrict__ bsum, int nb) {
    __shared__ int s[256];
    int t = threadIdx.x;
    int v = (t < nb) ? bsum[t] : 0;
    s[t] = v;
    __syncthreads();
    for (int off = 1; off < 256; off <<= 1) {
        int add = (t >= off) ? s[t - off] : 0;
        __syncthreads();
        s[t] += add;
        __syncthreads();
    }
    if (t < nb) bsum[t] = s[t] - v;  // exclusive
}

__global__ __launch_bounds__(256) void k_scan_c(const int* __restrict__ deg, int n,
                                                const int* __restrict__ bsum,
                                                int* __restrict__ rowptr,
                                                int* __restrict__ cursor, int E) {
    __shared__ int s[256];
    int t = threadIdx.x;
    int i = blockIdx.x * 256 + t;
    int v = (i < n) ? deg[i] : 0;
    s[t] = v;
    __syncthreads();
    for (int off = 1; off < 256; off <<= 1) {
        int add = (t >= off) ? s[t - off] : 0;
        __syncthreads();
        s[t] += add;
        __syncthreads();
    }
    if (i < n) {
        int ex = bsum[blockIdx.x] + s[t] - v;
        rowptr[i] = ex;
        cursor[i] = ex;
    }
    if (i == 0) rowptr[n] = E;
}

__global__ __launch_bounds__(256) void k_fill(const int* __restrict__ src,
                                              const int* __restrict__ dst, int E,
                                              int* __restrict__ cursor,
                                              int* __restrict__ csr_src) {
    int e = blockIdx.x * 256 + threadIdx.x;
    if (e < E) {
        int d = dst[e];
        int slot = atomicAdd(&cursor[d], 1);
        csr_src[slot] = src[e];
    }
}

// ---------------- fp32 -> fp16 conversions ----------------------------------
__global__ __launch_bounds__(256) void k_cvt(const float* __restrict__ in,
                                             u16* __restrict__ out, int nElem) {
    int i = (blockIdx.x * 256 + threadIdx.x) * 4;
    if (i >= nElem) return;
    float4 v = *(const float4*)(in + i);
    store4(out, i, v);
}

// Wt[c][k] = W[k][c] as fp16.  split==256: single W (row stride 256);
// split==128: c<128 from Wl, else Wr (row stride 128).
__global__ __launch_bounds__(256) void k_tw(const float* __restrict__ Wl,
                                            const float* __restrict__ Wr, int split,
                                            int K, u16* __restrict__ Wt) {
    int idx = blockIdx.x * 256 + threadIdx.x;
    if (idx >= 256 * K) return;
    int c = idx / K, k = idx - c * K;
    float v;
    if (split == 256)
        v = Wl[(size_t)k * 256 + c];
    else
        v = (c < 128) ? Wl[(size_t)k * 128 + c] : Wr[(size_t)k * 128 + (c - 128)];
    Wt[idx] = f2h(v);
}

// ---------------- MFMA GEMM + fused alpha epilogue --------------------------
// h[M,256](f16) = A[M,K](f16) @ W[K,256]; Wt = W^T fp16 [256][K].
// Block: 256 thr = 4 waves; wave w owns rows r0=blk*64+w*16; per K-chunk of 32
// all waves share Bs (256 cols x 32 k, rows padded to 40 halfwords: 16B-
// aligned ds_read_b128, <=2-way banks). mfma_f32_16x16x32_f16 layouts (HW-
// verified): A[m=lane&15][k=quad*8+j]; B[n=lane&15][k]; D col=lane&15,
// row=quad*4+reg. Epilogue computes as/ad[row,slot] from fp32 accs:
// ALOGW=5 -> 2 slots of 128 cols; ALOGW=4 -> 4 slots of 64 cols.
template <int K, int ALOGW>
__global__ __launch_bounds__(256) void k_gemm_mfma(
    const u16* __restrict__ Ah, const u16* __restrict__ Wt, u16* __restrict__ out,
    float* __restrict__ as_out, float* __restrict__ ad_out,
    const float* __restrict__ alo, const float* __restrict__ ahi,
    const float* __restrict__ dlo, const float* __restrict__ dhi, int M) {
    __shared__ u16 Bs[256 * 40];  // 20KB
    const int tid = threadIdx.x;
    const int wave = tid >> 6;
    const int lane = tid & 63;
    const int li = lane & 15;
    const int quad = lane >> 4;
    const int r0 = blockIdx.x * 64 + wave * 16;
    int arowi = r0 + li;
    if (arowi >= M) arowi = M - 1;  // clamp (stores are guarded)
    const u16* arow = Ah + (size_t)arowi * K + quad * 8;

    f32x4v acc[16];
#pragma unroll
    for (int ct = 0; ct < 16; ct++) acc[ct] = (f32x4v)(0.f);

    for (int t = 0; t < K; t += 32) {
        __syncthreads();  // prior chunk's ds_reads done
        // stage Wt[:, t..t+31]: thread tid stages row c=tid (64B = 4x uint4)
        {
            const u16* src = Wt + (size_t)tid * K + t;
            u16* dst = Bs + tid * 40;
            uint4 v0 = ((const uint4*)src)[0];
            uint4 v1 = ((const uint4*)src)[1];
            uint4 v2 = ((const uint4*)src)[2];
            uint4 v3 = ((const uint4*)src)[3];
            ((uint4*)dst)[0] = v0;
            ((uint4*)(dst + 8))[0] = v1;
            ((uint4*)(dst + 16))[0] = v2;
            ((uint4*)(dst + 24))[0] = v3;
        }
        __syncthreads();
        f16x8 a = *(const f16x8*)(arow + t);
#pragma unroll
        for (int ct = 0; ct < 16; ct++) {
            f16x8 b = *(const f16x8*)(Bs + (ct * 16 + li) * 40 + quad * 8);
            acc[ct] = __builtin_amdgcn_mfma_f32_16x16x32_f16(a, b, acc[ct], 0, 0, 0);
        }
    }

    // h store (fp16): D row = quad*4+reg, col = ct*16+li
#pragma unroll
    for (int reg = 0; reg < 4; reg++) {
        int grow = r0 + quad * 4 + reg;
        if (grow < M) {
            u16* orow = out + (size_t)grow * 256 + li;
#pragma unroll
            for (int ct = 0; ct < 16; ct++) orow[ct * 16] = f2h(acc[ct][reg]);
        }
    }

    // fused alpha epilogue
    const int NS = 64 >> ALOGW;   // 2 or 4
    const int SH = ALOGW - 2;     // slot = ct >> SH
    float aw[16], dw[16];
#pragma unroll
    for (int ct = 0; ct < 16; ct++) {
        int col = ct * 16 + li;
        aw[ct] = (col < 128) ? alo[col] : ahi[col - 128];
        dw[ct] = (col < 128) ? dlo[col] : dhi[col - 128];
    }
#pragma unroll
    for (int reg = 0; reg < 4; reg++) {
        float s[4] = {0.f, 0.f, 0.f, 0.f};
        float d[4] = {0.f, 0.f, 0.f, 0.f};
#pragma unroll
        for (int ct = 0; ct < 16; ct++) {
            int sl = ct >> SH;
            s[sl] += acc[ct][reg] * aw[ct];
            d[sl] += acc[ct][reg] * dw[ct];
        }
#pragma unroll
        for (int sl = 0; sl < NS; sl++) {
#pragma unroll
            for (int m = 1; m <= 8; m <<= 1) {
                s[sl] += __shfl_xor(s[sl], m, 64);
                d[sl] += __shfl_xor(d[sl], m, 64);
            }
        }
        int grow = r0 + quad * 4 + reg;
        if (li == 0 && grow < M) {
#pragma unroll
            for (int sl = 0; sl < NS; sl++) {
                as_out[(size_t)grow * NS + sl] = s[sl];
                ad_out[(size_t)grow * NS + sl] = d[sl];
            }
        }
    }
}

// ---------------- aggregation (softmax-weighted gather) ----------------------
// Column-half split with XCD-group affinity: blockIdx%8 -> XCD (round-robin
// dispatch); xcd<4 handles cols 0-127, xcd>=4 handles cols 128-255. Each wave
// owns one dst node's half-row; lane owns 2 channels (4B gather loads).
// Edge weights (as[src] load + leakyrelu + exp) recomputed per half -- as[] is
// <=800KB, L2-resident. Half-rows are 256B-aligned -> disjoint cache lines,
// so each XCD group only pulls its own half of h (12.8MB vs 25.6MB).
// MODE 0: +bias, ELU, write fp16 x1 [n,256]. MODE 1: +bias, write fp32 mu/ls.
template <int LOGW, int MODE, typename OT>
__global__ __launch_bounds__(256) void k_agg2(const u16* __restrict__ h,
                                              const int* __restrict__ rowptr,
                                              const int* __restrict__ csr_src,
                                              const float* __restrict__ as,
                                              const float* __restrict__ ad,
                                              const float* __restrict__ b_lo,
                                              const float* __restrict__ b_hi,
                                              OT* __restrict__ outp, int n,
                                              int nGrp) {
    const int NS = 64 >> LOGW;  // total alpha slots (2 or 4)
    const int bid = blockIdx.x;
    const int xcd = bid & 7;
    const int half = xcd >> 2;                  // 0: cols 0-127, 1: cols 128-255
    const int grp = (bid >> 3) * 4 + (xcd & 3); // dst group within half
    if (grp >= nGrp) return;
    const int wid = grp * 4 + (threadIdx.x >> 6);
    if (wid >= n) return;
    const int lane = threadIdx.x & 63;
    const int col = half * 128 + lane * 2;
    const int slot = col >> (LOGW + 2);

    float adv = ad[(size_t)wid * NS + slot];
    float e = as[(size_t)wid * NS + slot] + adv;  // self-loop
    e = fmaxf(e, 0.2f * e);                       // LeakyReLU(0.2)
    float w = __expf(e);
    float denom = w;
    float2 hv = loadh2(h, (size_t)wid * 256 + col);
    float acc0 = w * hv.x, acc1 = w * hv.y;

    const int rb = rowptr[wid], re = rowptr[wid + 1];
    int p = rb;
    for (; p + 4 <= re; p += 4) {
        int s0 = csr_src[p], s1 = csr_src[p + 1];
        int s2 = csr_src[p + 2], s3 = csr_src[p + 3];
        float e0 = as[(size_t)s0 * NS + slot] + adv;
        float e1 = as[(size_t)s1 * NS + slot] + adv;
        float e2 = as[(size_t)s2 * NS + slot] + adv;
        float e3 = as[(size_t)s3 * NS + slot] + adv;
        e0 = fmaxf(e0, 0.2f * e0);
        e1 = fmaxf(e1, 0.2f * e1);
        e2 = fmaxf(e2, 0.2f * e2);
        e3 = fmaxf(e3, 0.2f * e3);
        float w0 = __expf(e0), w1 = __expf(e1), w2 = __expf(e2), w3 = __expf(e3);
        float2 h0 = loadh2(h, (size_t)s0 * 256 + col);
        float2 h1 = loadh2(h, (size_t)s1 * 256 + col);
        float2 h2 = loadh2(h, (size_t)s2 * 256 + col);
        float2 h3 = loadh2(h, (size_t)s3 * 256 + col);
        denom += (w0 + w1) + (w2 + w3);
        acc0 += w0 * h0.x + w1 * h1.x + w2 * h2.x + w3 * h3.x;
        acc1 += w0 * h0.y + w1 * h1.y + w2 * h2.y + w3 * h3.y;
    }
    for (; p < re; ++p) {
        int s = csr_src[p];
        float ev = as[(size_t)s * NS + slot] + adv;
        ev = fmaxf(ev, 0.2f * ev);
        float ww = __expf(ev);
        denom += ww;
        float2 hh = loadh2(h, (size_t)s * 256 + col);
        acc0 += ww * hh.x;
        acc1 += ww * hh.y;
    }
    float inv = 1.0f / (denom + 1e-16f);

    const float* bp = half ? b_hi : b_lo;
    const int ci = lane * 2;
    float2 bv = *(const float2*)(bp + ci);
    float v0 = acc0 * inv + bv.x;
    float v1 = acc1 * inv + bv.y;

    if (MODE == 0) {  // ELU -> x1 fp16 [n,256]
        v0 = v0 > 0.f ? v0 : expm1f(v0);
        v1 = v1 > 0.f ? v1 : expm1f(v1);
        store2h((u16*)outp, (size_t)wid * 256 + col, v0, v1);
    } else {  // half 0 -> mu [n,128]; half 1 -> logstd [n,128] (concatenated)
        size_t base = half ? ((size_t)n * 128 + (size_t)wid * 128 + ci)
                           : ((size_t)wid * 128 + ci);
        *(float2*)((float*)outp + base) = make_float2(v0, v1);
    }
}

// ---------------------------------------------------------------------------
extern "C" void kernel_launch(void* const* d_in, const int* in_sizes, int n_in,
                              void* d_out, int out_size, void* d_ws, size_t ws_size,
                              hipStream_t stream) {
    const float* x = (const float*)d_in[0];
    const u32* ebuf = (const u32*)d_in[1];
    const float* W1 = (const float*)d_in[2];
    const float* a_src1 = (const float*)d_in[3];
    const float* a_dst1 = (const float*)d_in[4];
    const float* b1 = (const float*)d_in[5];
    const float* W_mu = (const float*)d_in[6];
    const float* a_src_mu = (const float*)d_in[7];
    const float* a_dst_mu = (const float*)d_in[8];
    const float* b_mu = (const float*)d_in[9];
    const float* W_ls = (const float*)d_in[10];
    const float* a_src_ls = (const float*)d_in[11];
    const float* a_dst_ls = (const float*)d_in[12];
    const float* b_ls = (const float*)d_in[13];

    const int n = in_sizes[0] / 128;  // 50000
    const int E = in_sizes[1] / 2;    // 800000

    char* base = (char*)d_ws;
    size_t off = 0;
    auto alloc = [&](size_t b) -> char* {
        char* p = base + off;
        off = (off + b + 255) & ~(size_t)255;
        return p;
    };
    int* rowptr = (int*)alloc((size_t)(n + 1) * 4);
    int* cursor = (int*)alloc((size_t)n * 4);
    int* csr = (int*)alloc((size_t)E * 4);
    int* bsum = (int*)alloc(256 * 4);
    int* eflag = (int*)alloc(256);
    int* se = (int*)alloc((size_t)E * 4);
    int* de = (int*)alloc((size_t)E * 4);
    float* as = (float*)alloc((size_t)n * 4 * 4);
    float* ad = (float*)alloc((size_t)n * 4 * 4);
    u16* W1t = (u16*)alloc(256 * 128 * 2);        // W1^T fp16 [256][128]
    u16* Wt2 = (u16*)alloc(256 * 256 * 2);        // [W_mu|W_ls]^T fp16 [256][256]
    u16* x1h = (u16*)alloc((size_t)n * 256 * 2);  // x1 fp16 [n,256]
    u16* xh = x1h;  // alias: xh fp16 [n,128] dead before x1h written
    u16* h = (u16*)alloc((size_t)n * 256 * 2);    // h fp16 (both layers)

    const int nb = (n + 255) / 256;
    const int eg = (E + 255) / 256;
    const int gg = (n + 63) / 64;
    const int nGrp = (n + 3) / 4;                 // dst groups per half
    const int aggGrid = 8 * ((nGrp + 3) / 4);     // 2 halves x 4-XCD groups

    // edge normalize + CSR build (reused by all three convs)
    hipMemsetAsync(cursor, 0, (size_t)n * 4, stream);
    k_detect<<<1, 256, 0, stream>>>(ebuf, eflag);
    k_extract<<<eg, 256, 0, stream>>>(ebuf, E, eflag, se, de, cursor);
    k_scan_a<<<nb, 256, 0, stream>>>(cursor, n, bsum);
    k_scan_b<<<1, 256, 0, stream>>>(bsum, nb);
    k_scan_c<<<nb, 256, 0, stream>>>(cursor, n, bsum, rowptr, cursor, E);
    k_fill<<<eg, 256, 0, stream>>>(se, de, E, cursor, csr);

    // fp16 conversions / weight transposes
    k_cvt<<<(n * 128 / 4 + 255) / 256, 256, 0, stream>>>(x, xh, n * 128);
    k_tw<<<(256 * 128 + 255) / 256, 256, 0, stream>>>(W1, W1, 256, 128, W1t);
    k_tw<<<(256 * 256 + 255) / 256, 256, 0, stream>>>(W_mu, W_ls, 128, 256, Wt2);

    // Layer 1: h = x@W1 (MFMA, fused alphas); aggregate -> ELU -> x1 (fp16)
    k_gemm_mfma<128, 5><<<gg, 256, 0, stream>>>(xh, W1t, h, as, ad, a_src1,
                                                a_src1 + 128, a_dst1, a_dst1 + 128,
                                                n);
    k_agg2<5, 0, u16><<<aggGrid, 256, 0, stream>>>(h, rowptr, csr, as, ad, b1,
                                                   b1 + 128, x1h, n, nGrp);

    // Layers mu & ls: h = x1@[W_mu|W_ls] (MFMA, fused alphas); aggregate
    k_gemm_mfma<256, 4><<<gg, 256, 0, stream>>>(x1h, Wt2, h, as, ad, a_src_mu,
                                                a_src_ls, a_dst_mu, a_dst_ls, n);
    k_agg2<4, 1, float><<<aggGrid, 256, 0, stream>>>(h, rowptr, csr, as, ad, b_mu,
                                                     b_ls, (float*)d_out, n, nGrp);
}

// Round 2
// 388.072 us; speedup vs baseline: 1.0751x; 1.0751x over previous
//
#include <hip/hip_runtime.h>

// ---------------------------------------------------------------------------
// GAT encoder: x --GATConv(2 heads,128)--> ELU --> {GATConv mu, GATConv ls}
// N=50000, E=800000 (+self loops). fp32 in/out. Edges int32 w/ int64 detect.
// Round 9:
//  * k_agg: column-half XCD affinity kept (FETCH 210->168MB, round 8), but
//    instruction density restored to round-7 level: each 32-lane half-wave
//    owns one dst node per column half, 4 channels/lane (8B gathers), one
//    exp per 4 channels. Round 8's 2-ch/lane split doubled VALU (44->72%)
//    and halved gather width -> issue-bound regression (68.6->82.3us).
//    Divergence cost of pairing two nodes per wave ~ E[max(d0,d1)]/E[d]~1.14.
//  * MFMA GEMM stages Wt chunks in LDS (20KB, pad-40 rows); alphas fused
//    into GEMM epilogue from fp32 accs (round 7).
// ---------------------------------------------------------------------------

typedef unsigned short u16;
typedef unsigned int u32;
typedef _Float16 f16;
typedef f16 f16x8 __attribute__((ext_vector_type(8)));
typedef float f32x4v __attribute__((ext_vector_type(4)));

__device__ __forceinline__ u16 f2h(float f) {
    union { f16 h; u16 u; } t;
    t.h = (f16)f;
    return t.u;
}
__device__ __forceinline__ float4 loadh4(const u16* __restrict__ p, size_t i) {
    union { uint2 u; f16 h[4]; } t;
    t.u = *(const uint2*)(p + i);
    return make_float4((float)t.h[0], (float)t.h[1], (float)t.h[2], (float)t.h[3]);
}
__device__ __forceinline__ void store4(float* __restrict__ p, size_t i, float4 v) {
    *(float4*)(p + i) = v;
}
__device__ __forceinline__ void store4(u16* __restrict__ p, size_t i, float4 v) {
    union { uint2 u; f16 h[4]; } t;
    t.h[0] = (f16)v.x; t.h[1] = (f16)v.y; t.h[2] = (f16)v.z; t.h[3] = (f16)v.w;
    *(uint2*)(p + i) = t.u;
}

// ---------------- edge dtype detect + normalize (+degree count) --------------
__global__ __launch_bounds__(256) void k_detect(const u32* __restrict__ ebuf,
                                                int* __restrict__ flag) {
    __shared__ int nz;
    if (threadIdx.x == 0) nz = 0;
    __syncthreads();
    if (ebuf[2 * threadIdx.x + 1] != 0u) atomicAdd(&nz, 1);
    __syncthreads();
    if (threadIdx.x == 0) *flag = (nz == 0) ? 1 : 0;
}

__global__ __launch_bounds__(256) void k_extract(const u32* __restrict__ ebuf, int E,
                                                 const int* __restrict__ flag,
                                                 int* __restrict__ se,
                                                 int* __restrict__ de,
                                                 int* __restrict__ deg) {
    int e = blockIdx.x * 256 + threadIdx.x;
    if (e >= E) return;
    int s, d;
    if (*flag) {  // int64 layout
        s = (int)ebuf[2 * (size_t)e];
        d = (int)ebuf[2 * ((size_t)E + (size_t)e)];
    } else {  // int32 layout
        s = (int)ebuf[e];
        d = (int)ebuf[(size_t)E + (size_t)e];
    }
    se[e] = s;
    de[e] = d;
    atomicAdd(&deg[d], 1);
}

// ---------------- CSR build ----------------
__global__ __launch_bounds__(256) void k_scan_a(const int* __restrict__ deg, int n,
                                                int* __restrict__ bsum) {
    __shared__ int s[256];
    int i = blockIdx.x * 256 + threadIdx.x;
    s[threadIdx.x] = (i < n) ? deg[i] : 0;
    __syncthreads();
    for (int st = 128; st > 0; st >>= 1) {
        if (threadIdx.x < st) s[threadIdx.x] += s[threadIdx.x + st];
        __syncthreads();
    }
    if (threadIdx.x == 0) bsum[blockIdx.x] = s[0];
}

__global__ __launch_bounds__(256) void k_scan_b(int* __restrict__ bsum, int nb) {
    __shared__ int s[256];
    int t = threadIdx.x;
    int v = (t < nb) ? bsum[t] : 0;
    s[t] = v;
    __syncthreads();
    for (int off = 1; off < 256; off <<= 1) {
        int add = (t >= off) ? s[t - off] : 0;
        __syncthreads();
        s[t] += add;
        __syncthreads();
    }
    if (t < nb) bsum[t] = s[t] - v;  // exclusive
}

__global__ __launch_bounds__(256) void k_scan_c(const int* __restrict__ deg, int n,
                                                const int* __restrict__ bsum,
                                                int* __restrict__ rowptr,
                                                int* __restrict__ cursor, int E) {
    __shared__ int s[256];
    int t = threadIdx.x;
    int i = blockIdx.x * 256 + t;
    int v = (i < n) ? deg[i] : 0;
    s[t] = v;
    __syncthreads();
    for (int off = 1; off < 256; off <<= 1) {
        int add = (t >= off) ? s[t - off] : 0;
        __syncthreads();
        s[t] += add;
        __syncthreads();
    }
    if (i < n) {
        int ex = bsum[blockIdx.x] + s[t] - v;
        rowptr[i] = ex;
        cursor[i] = ex;
    }
    if (i == 0) rowptr[n] = E;
}

__global__ __launch_bounds__(256) void k_fill(const int* __restrict__ src,
                                              const int* __restrict__ dst, int E,
                                              int* __restrict__ cursor,
                                              int* __restrict__ csr_src) {
    int e = blockIdx.x * 256 + threadIdx.x;
    if (e < E) {
        int d = dst[e];
        int slot = atomicAdd(&cursor[d], 1);
        csr_src[slot] = src[e];
    }
}

// ---------------- fp32 -> fp16 conversions ----------------------------------
__global__ __launch_bounds__(256) void k_cvt(const float* __restrict__ in,
                                             u16* __restrict__ out, int nElem) {
    int i = (blockIdx.x * 256 + threadIdx.x) * 4;
    if (i >= nElem) return;
    float4 v = *(const float4*)(in + i);
    store4(out, i, v);
}

// Wt[c][k] = W[k][c] as fp16.  split==256: single W (row stride 256);
// split==128: c<128 from Wl, else Wr (row stride 128).
__global__ __launch_bounds__(256) void k_tw(const float* __restrict__ Wl,
                                            const float* __restrict__ Wr, int split,
                                            int K, u16* __restrict__ Wt) {
    int idx = blockIdx.x * 256 + threadIdx.x;
    if (idx >= 256 * K) return;
    int c = idx / K, k = idx - c * K;
    float v;
    if (split == 256)
        v = Wl[(size_t)k * 256 + c];
    else
        v = (c < 128) ? Wl[(size_t)k * 128 + c] : Wr[(size_t)k * 128 + (c - 128)];
    Wt[idx] = f2h(v);
}

// ---------------- MFMA GEMM + fused alpha epilogue --------------------------
// h[M,256](f16) = A[M,K](f16) @ W[K,256]; Wt = W^T fp16 [256][K].
// Block: 256 thr = 4 waves; wave w owns rows r0=blk*64+w*16; per K-chunk of 32
// all waves share Bs (256 cols x 32 k, rows padded to 40 halfwords: 16B-
// aligned ds_read_b128, <=2-way banks). mfma_f32_16x16x32_f16 layouts (HW-
// verified): A[m=lane&15][k=quad*8+j]; B[n=lane&15][k]; D col=lane&15,
// row=quad*4+reg. Epilogue computes as/ad[row,slot] from fp32 accs:
// ALOGW=5 -> 2 slots of 128 cols; ALOGW=4 -> 4 slots of 64 cols.
template <int K, int ALOGW>
__global__ __launch_bounds__(256) void k_gemm_mfma(
    const u16* __restrict__ Ah, const u16* __restrict__ Wt, u16* __restrict__ out,
    float* __restrict__ as_out, float* __restrict__ ad_out,
    const float* __restrict__ alo, const float* __restrict__ ahi,
    const float* __restrict__ dlo, const float* __restrict__ dhi, int M) {
    __shared__ u16 Bs[256 * 40];  // 20KB
    const int tid = threadIdx.x;
    const int wave = tid >> 6;
    const int lane = tid & 63;
    const int li = lane & 15;
    const int quad = lane >> 4;
    const int r0 = blockIdx.x * 64 + wave * 16;
    int arowi = r0 + li;
    if (arowi >= M) arowi = M - 1;  // clamp (stores are guarded)
    const u16* arow = Ah + (size_t)arowi * K + quad * 8;

    f32x4v acc[16];
#pragma unroll
    for (int ct = 0; ct < 16; ct++) acc[ct] = (f32x4v)(0.f);

    for (int t = 0; t < K; t += 32) {
        __syncthreads();  // prior chunk's ds_reads done
        // stage Wt[:, t..t+31]: thread tid stages row c=tid (64B = 4x uint4)
        {
            const u16* src = Wt + (size_t)tid * K + t;
            u16* dst = Bs + tid * 40;
            uint4 v0 = ((const uint4*)src)[0];
            uint4 v1 = ((const uint4*)src)[1];
            uint4 v2 = ((const uint4*)src)[2];
            uint4 v3 = ((const uint4*)src)[3];
            ((uint4*)dst)[0] = v0;
            ((uint4*)(dst + 8))[0] = v1;
            ((uint4*)(dst + 16))[0] = v2;
            ((uint4*)(dst + 24))[0] = v3;
        }
        __syncthreads();
        f16x8 a = *(const f16x8*)(arow + t);
#pragma unroll
        for (int ct = 0; ct < 16; ct++) {
            f16x8 b = *(const f16x8*)(Bs + (ct * 16 + li) * 40 + quad * 8);
            acc[ct] = __builtin_amdgcn_mfma_f32_16x16x32_f16(a, b, acc[ct], 0, 0, 0);
        }
    }

    // h store (fp16): D row = quad*4+reg, col = ct*16+li
#pragma unroll
    for (int reg = 0; reg < 4; reg++) {
        int grow = r0 + quad * 4 + reg;
        if (grow < M) {
            u16* orow = out + (size_t)grow * 256 + li;
#pragma unroll
            for (int ct = 0; ct < 16; ct++) orow[ct * 16] = f2h(acc[ct][reg]);
        }
    }

    // fused alpha epilogue
    const int NS = 64 >> ALOGW;   // 2 or 4
    const int SH = ALOGW - 2;     // slot = ct >> SH
    float aw[16], dw[16];
#pragma unroll
    for (int ct = 0; ct < 16; ct++) {
        int col = ct * 16 + li;
        aw[ct] = (col < 128) ? alo[col] : ahi[col - 128];
        dw[ct] = (col < 128) ? dlo[col] : dhi[col - 128];
    }
#pragma unroll
    for (int reg = 0; reg < 4; reg++) {
        float s[4] = {0.f, 0.f, 0.f, 0.f};
        float d[4] = {0.f, 0.f, 0.f, 0.f};
#pragma unroll
        for (int ct = 0; ct < 16; ct++) {
            int sl = ct >> SH;
            s[sl] += acc[ct][reg] * aw[ct];
            d[sl] += acc[ct][reg] * dw[ct];
        }
#pragma unroll
        for (int sl = 0; sl < NS; sl++) {
#pragma unroll
            for (int m = 1; m <= 8; m <<= 1) {
                s[sl] += __shfl_xor(s[sl], m, 64);
                d[sl] += __shfl_xor(d[sl], m, 64);
            }
        }
        int grow = r0 + quad * 4 + reg;
        if (li == 0 && grow < M) {
#pragma unroll
            for (int sl = 0; sl < NS; sl++) {
                as_out[(size_t)grow * NS + sl] = s[sl];
                ad_out[(size_t)grow * NS + sl] = d[sl];
            }
        }
    }
}

// ---------------- aggregation (softmax-weighted gather) ----------------------
// Column-half split with XCD-group affinity: blockIdx%8 -> XCD (round-robin
// dispatch); xcd<4 -> cols 0-127, xcd>=4 -> cols 128-255. Each 32-lane
// half-wave owns ONE dst node for its half: lane owns 4 channels (8B gather
// loads), one exp per 4 channels (round-7 instruction density). The two
// half-waves of a wave have independent degrees; divergence cost
// ~E[max(d0,d1)]/E[d] ~ 1.14 for Poisson(16).
// Block = 4 waves = 8 dst nodes per half. Edge weights recomputed per half
// (as[] <=800KB, L2-resident). Half-rows are 256B-aligned -> disjoint lines,
// so each XCD group pulls only its 12.8MB half of h.
// MODE 0: +bias, ELU, write fp16 x1 [n,256]. MODE 1: +bias, write fp32 mu/ls.
template <int LOGW, int MODE, typename OT>
__global__ __launch_bounds__(256) void k_agg3(const u16* __restrict__ h,
                                              const int* __restrict__ rowptr,
                                              const int* __restrict__ csr_src,
                                              const float* __restrict__ as,
                                              const float* __restrict__ ad,
                                              const float* __restrict__ b_lo,
                                              const float* __restrict__ b_hi,
                                              OT* __restrict__ outp, int n,
                                              int nGrp) {
    const int NS = 64 >> LOGW;  // total alpha slots (2 or 4)
    const int bid = blockIdx.x;
    const int xcd = bid & 7;
    const int half = xcd >> 2;                  // 0: cols 0-127, 1: cols 128-255
    const int grp = (bid >> 3) * 4 + (xcd & 3); // node group within half
    if (grp >= nGrp) return;
    const int lane = threadIdx.x & 63;
    const int sub = lane >> 5;   // which node of the wave's pair
    const int sl = lane & 31;    // lane within the node
    const int wid0 = grp * 8 + (threadIdx.x >> 6) * 2 + sub;
    const bool ok = wid0 < n;
    const int wid = ok ? wid0 : (n - 1);  // clamped for safe loads
    const int col = half * 128 + sl * 4;
    const int slot = col >> (LOGW + 2);

    float adv = ad[(size_t)wid * NS + slot];
    float e = as[(size_t)wid * NS + slot] + adv;  // self-loop
    e = fmaxf(e, 0.2f * e);                       // LeakyReLU(0.2)
    float w = __expf(e);
    float denom = w;
    float4 hv = loadh4(h, (size_t)wid * 256 + col);
    float acc0 = w * hv.x, acc1 = w * hv.y, acc2 = w * hv.z, acc3 = w * hv.w;

    int rb = 0, re = 0;
    if (ok) { rb = rowptr[wid0]; re = rowptr[wid0 + 1]; }
    int p = rb;
    for (; p + 4 <= re; p += 4) {
        int s0 = csr_src[p], s1 = csr_src[p + 1];
        int s2 = csr_src[p + 2], s3 = csr_src[p + 3];
        float e0 = as[(size_t)s0 * NS + slot] + adv;
        float e1 = as[(size_t)s1 * NS + slot] + adv;
        float e2 = as[(size_t)s2 * NS + slot] + adv;
        float e3 = as[(size_t)s3 * NS + slot] + adv;
        e0 = fmaxf(e0, 0.2f * e0);
        e1 = fmaxf(e1, 0.2f * e1);
        e2 = fmaxf(e2, 0.2f * e2);
        e3 = fmaxf(e3, 0.2f * e3);
        float w0 = __expf(e0), w1 = __expf(e1), w2 = __expf(e2), w3 = __expf(e3);
        float4 h0 = loadh4(h, (size_t)s0 * 256 + col);
        float4 h1 = loadh4(h, (size_t)s1 * 256 + col);
        float4 h2 = loadh4(h, (size_t)s2 * 256 + col);
        float4 h3 = loadh4(h, (size_t)s3 * 256 + col);
        denom += (w0 + w1) + (w2 + w3);
        acc0 += w0 * h0.x + w1 * h1.x + w2 * h2.x + w3 * h3.x;
        acc1 += w0 * h0.y + w1 * h1.y + w2 * h2.y + w3 * h3.y;
        acc2 += w0 * h0.z + w1 * h1.z + w2 * h2.z + w3 * h3.z;
        acc3 += w0 * h0.w + w1 * h1.w + w2 * h2.w + w3 * h3.w;
    }
    for (; p < re; ++p) {
        int s = csr_src[p];
        float ev = as[(size_t)s * NS + slot] + adv;
        ev = fmaxf(ev, 0.2f * ev);
        float ww = __expf(ev);
        denom += ww;
        float4 hh = loadh4(h, (size_t)s * 256 + col);
        acc0 += ww * hh.x;
        acc1 += ww * hh.y;
        acc2 += ww * hh.z;
        acc3 += ww * hh.w;
    }
    float inv = 1.0f / (denom + 1e-16f);

    const float* bp = half ? b_hi : b_lo;
    const int ci = sl * 4;
    float4 bv = *(const float4*)(bp + ci);
    float v0 = acc0 * inv + bv.x;
    float v1 = acc1 * inv + bv.y;
    float v2 = acc2 * inv + bv.z;
    float v3 = acc3 * inv + bv.w;

    if (!ok) return;
    if (MODE == 0) {  // ELU -> x1 fp16 [n,256]
        v0 = v0 > 0.f ? v0 : expm1f(v0);
        v1 = v1 > 0.f ? v1 : expm1f(v1);
        v2 = v2 > 0.f ? v2 : expm1f(v2);
        v3 = v3 > 0.f ? v3 : expm1f(v3);
        store4((u16*)outp, (size_t)wid0 * 256 + col, make_float4(v0, v1, v2, v3));
    } else {  // half 0 -> mu [n,128]; half 1 -> logstd [n,128] (concatenated)
        size_t base = half ? ((size_t)n * 128 + (size_t)wid0 * 128 + ci)
                           : ((size_t)wid0 * 128 + ci);
        store4((float*)outp, base, make_float4(v0, v1, v2, v3));
    }
}

// ---------------------------------------------------------------------------
extern "C" void kernel_launch(void* const* d_in, const int* in_sizes, int n_in,
                              void* d_out, int out_size, void* d_ws, size_t ws_size,
                              hipStream_t stream) {
    const float* x = (const float*)d_in[0];
    const u32* ebuf = (const u32*)d_in[1];
    const float* W1 = (const float*)d_in[2];
    const float* a_src1 = (const float*)d_in[3];
    const float* a_dst1 = (const float*)d_in[4];
    const float* b1 = (const float*)d_in[5];
    const float* W_mu = (const float*)d_in[6];
    const float* a_src_mu = (const float*)d_in[7];
    const float* a_dst_mu = (const float*)d_in[8];
    const float* b_mu = (const float*)d_in[9];
    const float* W_ls = (const float*)d_in[10];
    const float* a_src_ls = (const float*)d_in[11];
    const float* a_dst_ls = (const float*)d_in[12];
    const float* b_ls = (const float*)d_in[13];

    const int n = in_sizes[0] / 128;  // 50000
    const int E = in_sizes[1] / 2;    // 800000

    char* base = (char*)d_ws;
    size_t off = 0;
    auto alloc = [&](size_t b) -> char* {
        char* p = base + off;
        off = (off + b + 255) & ~(size_t)255;
        return p;
    };
    int* rowptr = (int*)alloc((size_t)(n + 1) * 4);
    int* cursor = (int*)alloc((size_t)n * 4);
    int* csr = (int*)alloc((size_t)E * 4);
    int* bsum = (int*)alloc(256 * 4);
    int* eflag = (int*)alloc(256);
    int* se = (int*)alloc((size_t)E * 4);
    int* de = (int*)alloc((size_t)E * 4);
    float* as = (float*)alloc((size_t)n * 4 * 4);
    float* ad = (float*)alloc((size_t)n * 4 * 4);
    u16* W1t = (u16*)alloc(256 * 128 * 2);        // W1^T fp16 [256][128]
    u16* Wt2 = (u16*)alloc(256 * 256 * 2);        // [W_mu|W_ls]^T fp16 [256][256]
    u16* x1h = (u16*)alloc((size_t)n * 256 * 2);  // x1 fp16 [n,256]
    u16* xh = x1h;  // alias: xh fp16 [n,128] dead before x1h written
    u16* h = (u16*)alloc((size_t)n * 256 * 2);    // h fp16 (both layers)

    const int nb = (n + 255) / 256;
    const int eg = (E + 255) / 256;
    const int gg = (n + 63) / 64;
    const int nGrp = (n + 7) / 8;                 // 8 dst nodes per block/half
    const int aggGrid = 8 * ((nGrp + 3) / 4);     // 2 halves x 4-XCD groups

    // edge normalize + CSR build (reused by all three convs)
    hipMemsetAsync(cursor, 0, (size_t)n * 4, stream);
    k_detect<<<1, 256, 0, stream>>>(ebuf, eflag);
    k_extract<<<eg, 256, 0, stream>>>(ebuf, E, eflag, se, de, cursor);
    k_scan_a<<<nb, 256, 0, stream>>>(cursor, n, bsum);
    k_scan_b<<<1, 256, 0, stream>>>(bsum, nb);
    k_scan_c<<<nb, 256, 0, stream>>>(cursor, n, bsum, rowptr, cursor, E);
    k_fill<<<eg, 256, 0, stream>>>(se, de, E, cursor, csr);

    // fp16 conversions / weight transposes
    k_cvt<<<(n * 128 / 4 + 255) / 256, 256, 0, stream>>>(x, xh, n * 128);
    k_tw<<<(256 * 128 + 255) / 256, 256, 0, stream>>>(W1, W1, 256, 128, W1t);
    k_tw<<<(256 * 256 + 255) / 256, 256, 0, stream>>>(W_mu, W_ls, 128, 256, Wt2);

    // Layer 1: h = x@W1 (MFMA, fused alphas); aggregate -> ELU -> x1 (fp16)
    k_gemm_mfma<128, 5><<<gg, 256, 0, stream>>>(xh, W1t, h, as, ad, a_src1,
                                                a_src1 + 128, a_dst1, a_dst1 + 128,
                                                n);
    k_agg3<5, 0, u16><<<aggGrid, 256, 0, stream>>>(h, rowptr, csr, as, ad, b1,
                                                   b1 + 128, x1h, n, nGrp);

    // Layers mu & ls: h = x1@[W_mu|W_ls] (MFMA, fused alphas); aggregate
    k_gemm_mfma<256, 4><<<gg, 256, 0, stream>>>(x1h, Wt2, h, as, ad, a_src_mu,
                                                a_src_ls, a_dst_mu, a_dst_ls, n);
    k_agg3<4, 1, float><<<aggGrid, 256, 0, stream>>>(h, rowptr, csr, as, ad, b_mu,
                                                     b_ls, (float*)d_out, n, nGrp);
}